// Round 4
// baseline (74.160 us; speedup 1.0000x reference)
//
#include <hip/hip_runtime.h>
#include <math.h>

#define NBOX 2048
#define NBATCH 8
#define MAX_INST 100
#define MIN_CONF 0.15f
#define NMS_THR 0.3f
#define BLOCK 512
#define NWAVE (BLOCK / 64)

typedef unsigned long long ull;

// Decode one box exactly in the reference's f32 op order (no FMA contraction).
__device__ inline float4 decode_box(float4 r, float4 d,
                                    float wy1, float wx1, float wy2, float wx2) {
    float h  = __fsub_rn(r.z, r.x);
    float w  = __fsub_rn(r.w, r.y);
    float dy = __fmul_rn(d.x, 0.1f);
    float dx = __fmul_rn(d.y, 0.1f);
    float dh = __fmul_rn(d.z, 0.2f);
    float dw = __fmul_rn(d.w, 0.2f);
    float cy = __fadd_rn(__fadd_rn(r.x, __fmul_rn(0.5f, h)), __fmul_rn(dy, h));
    float cx = __fadd_rn(__fadd_rn(r.y, __fmul_rn(0.5f, w)), __fmul_rn(dx, w));
    float h2 = __fmul_rn(h, expf(dh));
    float w2 = __fmul_rn(w, expf(dw));
    float y1 = __fsub_rn(cy, __fmul_rn(0.5f, h2));
    float x1 = __fsub_rn(cx, __fmul_rn(0.5f, w2));
    float y2 = __fadd_rn(y1, h2);
    float x2 = __fadd_rn(x1, w2);
    float4 b;
    b.x = fminf(fmaxf(y1, wy1), wy2);
    b.y = fminf(fmaxf(x1, wx1), wx2);
    b.z = fminf(fmaxf(y2, wy1), wy2);
    b.w = fminf(fmaxf(x2, wx1), wx2);
    return b;
}

// Exact reference op order (IoU is symmetric in its two boxes).
__device__ inline float iou_pair(float4 a, float4 b) {
    float areaA = __fmul_rn(__fsub_rn(a.z, a.x), __fsub_rn(a.w, a.y));
    float areaB = __fmul_rn(__fsub_rn(b.z, b.x), __fsub_rn(b.w, b.y));
    float iy1 = fmaxf(a.x, b.x);
    float ix1 = fmaxf(a.y, b.y);
    float iy2 = fminf(a.z, b.z);
    float ix2 = fminf(a.w, b.w);
    float ih = fmaxf(__fsub_rn(iy2, iy1), 0.0f);
    float iw = fmaxf(__fsub_rn(ix2, ix1), 0.0f);
    float inter = __fmul_rn(ih, iw);
    float uni = __fadd_rn(__fsub_rn(__fadd_rn(areaA, areaB), inter), 1e-8f);
    return __fdiv_rn(inter, uni);
}

__device__ inline ull shfl_xor64(ull x, int d) {
    unsigned lo = (unsigned)x, hi = (unsigned)(x >> 32);
    lo = __shfl_xor(lo, d);
    hi = __shfl_xor(hi, d);
    return ((ull)hi << 32) | lo;
}

__device__ inline ull shfl64(ull x, int src) {
    unsigned lo = (unsigned)x, hi = (unsigned)(x >> 32);
    lo = __shfl(lo, src);
    hi = __shfl(hi, src);
    return ((ull)hi << 32) | lo;
}

__device__ inline void cmpsel(ull& a, ull& b, bool takeMinA) {
    ull mn = a < b ? a : b;
    ull mx = a < b ? b : a;
    a = takeMinA ? mn : mx;
    b = takeMinA ? mx : mn;
}

__global__ __launch_bounds__(BLOCK)
void detect_refine_kernel(const float* __restrict__ rois,
                          const float* __restrict__ scores_in,
                          const float* __restrict__ deltas,
                          const float* __restrict__ window,
                          float* __restrict__ out) {
    const int b    = blockIdx.x;
    const int tid  = threadIdx.x;
    const int lane = tid & 63;
    const int wid  = tid >> 6;

    __shared__ ull    keys[NBOX];        // 16 KiB  (~score_bits)<<32 | orig_idx
    __shared__ float4 sboxes[NBOX];      // 32 KiB  decoded boxes, by ORIGINAL idx
    __shared__ float  sscores[NBOX];     //  8 KiB  by ORIGINAL idx
    __shared__ int    aliveIdx[NBOX];    //  8 KiB  compacted alive orig-indices
    __shared__ ull    masks[64];
    __shared__ ull    s_chunkMask[32];
    __shared__ int    s_chunkCnt[32];
    __shared__ int    s_chunkOff[32];
    __shared__ int    s_aliveCount;
    __shared__ float4 s_keptbox[MAX_INST];
    __shared__ int    s_keptslot[64];
    __shared__ int    s_m;

    const float wy1 = window[b * 4 + 0];
    const float wx1 = window[b * 4 + 1];
    const float wy2 = window[b * 4 + 2];
    const float wx2 = window[b * 4 + 3];

    float* outb = out + (size_t)b * MAX_INST * 5;
    for (int i = tid; i < MAX_INST * 5; i += BLOCK) outb[i] = 0.0f;

    // ---- Phase A1: coalesced load + decode, stored by ORIGINAL index ----
    for (int e = tid; e < NBOX; e += BLOCK) {
        float4 r = ((const float4*)rois)[b * NBOX + e];
        float4 d = ((const float4*)deltas)[b * NBOX + e];
        float  s = scores_in[b * NBOX + e];
        sboxes[e]  = decode_box(r, d, wy1, wx1, wy2, wx2);
        sscores[e] = s;
    }

    // ---- Phase A2: sort keys in registers (4 consecutive elements/thread) ----
    const int e0 = tid * 4;
    ull v[4];
    {
        float4 sc = ((const float4*)(scores_in + (size_t)b * NBOX))[tid];
        float s4[4] = {sc.x, sc.y, sc.z, sc.w};
#pragma unroll
        for (int s = 0; s < 4; ++s) {
            unsigned u = __float_as_uint(s4[s]);
            u = (u & 0x80000000u) ? ~u : (u | 0x80000000u);
            v[s] = ((ull)(~u) << 32) | (unsigned)(e0 + s);
        }
    }

    // ---- Phase B: bitonic sort ascending (= score descending, stable) ----
    for (unsigned k = 2; k <= NBOX; k <<= 1) {
        if (k >= 512) {
#pragma unroll
            for (int s = 0; s < 4; ++s) keys[e0 + s] = v[s];
            __syncthreads();
            for (unsigned j = k >> 1; j >= 256; j >>= 1) {
                for (int t = tid; t < NBOX / 2; t += BLOCK) {
                    int i = 2 * t - (t & (j - 1));
                    int p = i | j;
                    bool up = ((i & k) == 0);
                    ull a = keys[i], c = keys[p];
                    bool sw = up ? (a > c) : (a < c);
                    if (sw) { keys[i] = c; keys[p] = a; }
                }
                __syncthreads();
            }
#pragma unroll
            for (int s = 0; s < 4; ++s) v[s] = keys[e0 + s];
        }
        unsigned jstart = ((k >> 1) > 128u) ? 128u : (k >> 1);
        for (unsigned j = jstart; j >= 4; j >>= 1) {
            int d = (int)(j >> 2);
#pragma unroll
            for (int s = 0; s < 4; ++s) {
                ull p = shfl_xor64(v[s], d);
                int e = e0 + s;
                bool takeMin = (((e & j) == 0) == ((e & k) == 0));
                v[s] = takeMin ? (v[s] < p ? v[s] : p) : (v[s] > p ? v[s] : p);
            }
        }
        if (k >= 4) {   // j == 2
            bool up = ((e0 & k) == 0);
            cmpsel(v[0], v[2], up);
            cmpsel(v[1], v[3], up);
        }
        {               // j == 1
            bool upA = ((e0 & k) == 0);
            bool upB = (((e0 + 2) & k) == 0);
            cmpsel(v[0], v[1], upA);
            cmpsel(v[2], v[3], upB);
        }
    }
#pragma unroll
    for (int s = 0; s < 4; ++s) keys[e0 + s] = v[s];
    __syncthreads();

    // ---- Phase C0: build compact alive list (orig indices, sorted order) ----
#pragma unroll
    for (int r = 0; r < 4; ++r) {
        int c = wid + r * NWAVE;           // c in [0,32)
        int oi = (int)(keys[c * 64 + lane] & 0xFFFFFFFFull);
        bool alive = (sscores[oi] >= MIN_CONF);
        ull bal = __ballot(alive);
        if (lane == 0) { s_chunkMask[c] = bal; s_chunkCnt[c] = __popcll(bal); }
    }
    __syncthreads();
    if (tid == 0) {
        int acc = 0;
        for (int c = 0; c < 32; ++c) { s_chunkOff[c] = acc; acc += s_chunkCnt[c]; }
        s_aliveCount = acc;
    }
    __syncthreads();
#pragma unroll
    for (int r = 0; r < 4; ++r) {
        int c = wid + r * NWAVE;
        int oi = (int)(keys[c * 64 + lane] & 0xFFFFFFFFull);
        ull msk = s_chunkMask[c];
        if ((msk >> lane) & 1ull)
            aliveIdx[s_chunkOff[c] + __popcll(msk & ((1ull << lane) - 1ull))] = oi;
    }
    __syncthreads();

    // ---- Phase C: dense-window greedy NMS over the alive list ----
    int A = s_aliveCount;
    int count = 0;
    while (A > 0 && count < MAX_INST) {
        const int W = (A < 64) ? A : 64;

        // 64x64 (WxW) IoU>thr mask rows, 8 rows per wave.
        int    cj = (lane < W) ? aliveIdx[lane] : aliveIdx[0];
        float4 bj = sboxes[cj];
        for (int i = wid; i < W; i += NWAVE) {
            float4 bi = sboxes[aliveIdx[i]];
            bool pred = (lane > i) && (lane < W) && (iou_pair(bi, bj) > NMS_THR);
            ull mrow = __ballot(pred);
            if (lane == 0) masks[i] = mrow;
        }
        __syncthreads();

        // Wave 0: greedy chain in registers (all W candidates are alive).
        if (wid == 0) {
            ull alive  = (W >= 64) ? ~0ull : ((1ull << W) - 1ull);
            ull mymask = (lane < W) ? masks[lane] : 0ull;
            int m = 0;
            const int maxm = MAX_INST - count;
            while (alive && m < maxm) {
                int i = __builtin_ctzll(alive);
                if (lane == 0) s_keptslot[m] = i;
                ++m;
                ull mi = shfl64(mymask, i);
                alive = alive & ~mi & ~(1ull << i);
            }
            if (lane == 0) s_m = m;
        }
        __syncthreads();

        const int m = s_m;
        if (tid < m) {
            int oi = aliveIdx[s_keptslot[tid]];
            float4 bb = sboxes[oi];
            s_keptbox[count + tid] = bb;
            float* o = outb + (size_t)(count + tid) * 5;
            o[0] = bb.x; o[1] = bb.y; o[2] = bb.z; o[3] = bb.w;
            o[4] = sscores[oi];
        }
        const int T = A - W;            // tail length
        count += m;
        if (count >= MAX_INST || T == 0) break;
        __syncthreads();                // s_keptbox visible to sweep

        // Sweep tail vs this round's m new keeps; snapshot + ballot per chunk.
        // T <= 1984 -> nch <= 31 -> at most 4 chunks per wave (unrolled, regs).
        const int nch = (T + 63) >> 6;
        int  myval[4];
        bool mykeep[4];
#pragma unroll
        for (int r = 0; r < 4; ++r) {
            int c = wid + r * NWAVE;
            bool keep = false; int val = 0;
            if (c < nch) {
                int e = 64 + c * 64 + lane;     // W == 64 here (T > 0)
                if (e < A) {
                    val = aliveIdx[e];
                    float4 cb = sboxes[val];
                    bool sup = false;
                    for (int kk = count - m; kk < count; ++kk)
                        sup |= (iou_pair(s_keptbox[kk], cb) > NMS_THR);
                    keep = !sup;
                }
                ull bal = __ballot(keep);
                if (lane == 0) { s_chunkMask[c] = bal; s_chunkCnt[c] = __popcll(bal); }
            }
            myval[r] = val; mykeep[r] = keep;
        }
        __syncthreads();
        if (tid == 0) {
            int acc = 0;
            for (int c = 0; c < nch; ++c) { s_chunkOff[c] = acc; acc += s_chunkCnt[c]; }
            s_aliveCount = acc;
        }
        __syncthreads();
#pragma unroll
        for (int r = 0; r < 4; ++r) {
            int c = wid + r * NWAVE;
            if (c < nch && mykeep[r]) {
                ull msk = s_chunkMask[c];
                aliveIdx[s_chunkOff[c] + __popcll(msk & ((1ull << lane) - 1ull))] = myval[r];
            }
        }
        __syncthreads();
        A = s_aliveCount;
    }
}

extern "C" void kernel_launch(void* const* d_in, const int* in_sizes, int n_in,
                              void* d_out, int out_size, void* d_ws, size_t ws_size,
                              hipStream_t stream) {
    const float* rois    = (const float*)d_in[0];
    const float* scores  = (const float*)d_in[1];
    const float* deltas  = (const float*)d_in[2];
    const float* window  = (const float*)d_in[3];
    float* out = (float*)d_out;
    detect_refine_kernel<<<NBATCH, BLOCK, 0, stream>>>(rois, scores, deltas, window, out);
}